// Round 1
// 545.490 us; speedup vs baseline: 1.1241x; 1.1241x over previous
//
#include <hip/hip_runtime.h>

// SVDAdapter: out = x @ (W + U*s*V^T)^T
// x: (8192,4096) f32, W: (4096,4096) f32, U: (4096,16), s: (16), V: (4096,16)
// Fast path: Wa = W + (U s) V^T rounded to f16; x rounded to f16; single-plane
// f16 MFMA GEMM (numerics identical to prior 617us kernel: absmax pinned 8.0).
// GEMM is the 256^2 8-phase counted-vmcnt schedule (T2+T3+T4+T5 stack):
//   - 8 waves (512 thr), BK=64, 128 KiB LDS as 8 half-tile regions
//     (2 buffers x {A_k0,B_k0,A_k1,B_k1}), global_load_lds staging with
//     pre-swizzled global source (chunk ^= (row>>1)&3, conflict-free b128 reads)
//   - one s_waitcnt vmcnt(6) per K-tile (3 half-tiles stay in flight across
//     barriers); raw s_barrier + asm lgkmcnt(0) + sched_barrier(0) (rule 18);
//     s_setprio(1) around each 16-MFMA cluster
//   - staging rotation (verified WAR/RAW): t.P1 stages A_k1(t+1),
//     t.P2 B_k0(t+2), t.P3 A_k0(t+2), t.P4 B_k1(t+2); last 2 tiles drain.
// Prep: split_x + prep_w fused into one dispatch (overlap instead of serialize).
// Fallback (ws too small): fp32 VALU GEMM + rank-16 fixup (unchanged).

#define IN_F   4096
#define OUT_F  4096
#define RANK   16
#define M_ROWS 8192
#define BM 256
#define BN 256
#define BK 64
#define NT (IN_F / BK)   // 64 K-tiles

typedef _Float16 f16x8 __attribute__((ext_vector_type(8)));
typedef _Float16 f16x4 __attribute__((ext_vector_type(4)));
typedef float    f32x4 __attribute__((ext_vector_type(4)));

// ---------------------------------------------------------------- async copy
__device__ __forceinline__ void async16(const void* gp, void* lp) {
  __builtin_amdgcn_global_load_lds(
      (const __attribute__((address_space(1))) void*)gp,
      (__attribute__((address_space(3))) void*)lp, 16, 0, 0);
}

// ---------------------------------------------------------------- fused prep
// blocks [0, 4096):   x (f32) -> xh (f16), grid-stride, 8 float4 per thread
// blocks [4096, 6144): wh[o][i] = f16( W[o][i] + sum_r U[o][r]*s[r]*V[i][r] )
#define SPLIT_BLOCKS 4096

__global__ __launch_bounds__(256)
void prep_kernel(const float* __restrict__ x, _Float16* __restrict__ xh,
                 const float* __restrict__ W, const float* __restrict__ U,
                 const float* __restrict__ S, const float* __restrict__ V,
                 _Float16* __restrict__ wh) {
  if (blockIdx.x < SPLIT_BLOCKS) {
    size_t t = (size_t)blockIdx.x * 256 + threadIdx.x;
#pragma unroll
    for (int it = 0; it < 8; ++it) {   // 8192*4096/4 / (4096*256) = 8
      float4 v = ((const float4*)x)[t];
      f16x4 h;
      h[0] = (_Float16)v.x; h[1] = (_Float16)v.y;
      h[2] = (_Float16)v.z; h[3] = (_Float16)v.w;
      ((f16x4*)xh)[t] = h;
      t += (size_t)SPLIT_BLOCKS * 256;
    }
  } else {
    int t = (int)(blockIdx.x - SPLIT_BLOCKS) * 256 + threadIdx.x;  // < 1024*512
    int i4 = (t & 1023) << 2;                 // i column group
    int o0 = (t >> 10) << 3;                  // 8 o-rows per thread

    float v[4][RANK];
#pragma unroll
    for (int j = 0; j < 4; ++j) {
      const float4* vp = (const float4*)(V + (size_t)(i4 + j) * RANK);
#pragma unroll
      for (int q = 0; q < 4; ++q) {
        float4 vv = vp[q];
        v[j][q * 4 + 0] = vv.x; v[j][q * 4 + 1] = vv.y;
        v[j][q * 4 + 2] = vv.z; v[j][q * 4 + 3] = vv.w;
      }
    }
    float sv[RANK];
#pragma unroll
    for (int r = 0; r < RANK; r += 4) {
      float4 ss = *(const float4*)(S + r);
      sv[r] = ss.x; sv[r + 1] = ss.y; sv[r + 2] = ss.z; sv[r + 3] = ss.w;
    }

    for (int oo = 0; oo < 8; ++oo) {
      int o = o0 + oo;
      float us[RANK];
      const float4* up = (const float4*)(U + (size_t)o * RANK);
#pragma unroll
      for (int r = 0; r < RANK; r += 4) {
        float4 uu = up[r >> 2];
        us[r] = uu.x * sv[r]; us[r + 1] = uu.y * sv[r + 1];
        us[r + 2] = uu.z * sv[r + 2]; us[r + 3] = uu.w * sv[r + 3];
      }
      float4 w = *(const float4*)(W + (size_t)o * IN_F + i4);
      float d0 = w.x, d1 = w.y, d2 = w.z, d3 = w.w;
#pragma unroll
      for (int r = 0; r < RANK; ++r) {
        d0 += us[r] * v[0][r];
        d1 += us[r] * v[1][r];
        d2 += us[r] * v[2][r];
        d3 += us[r] * v[3][r];
      }
      f16x4 h;
      h[0] = (_Float16)d0; h[1] = (_Float16)d1;
      h[2] = (_Float16)d2; h[3] = (_Float16)d3;
      *(f16x4*)(wh + (size_t)o * IN_F + i4) = h;
    }
  }
}

// ---------------------------------------------------------------- GEMM (fast)
// out[m][o] = sum_k xh[m][k]*wh[o][k]  ("NT": both operands K-major)
// 256x256 tile, BK=64, 8 waves (2M x 4N), per-wave 128x64 via 8x4 16x16x32
// f16 MFMA frags. LDS: 8 regions of 16 KiB (256 rows x 64B):
//   buf p @ p*65536:  A_k0 +0, B_k0 +16384, A_k1 +32768, B_k1 +49152
// Rows are 4 chunks of 16B, stored chunk c holds data chunk c ^ ((r>>1)&3)
// (swizzle applied on the GLOBAL gather; global_load_lds dest stays linear).
__global__ __launch_bounds__(512, 2)
void gemm_kernel(const _Float16* __restrict__ xh,
                 const _Float16* __restrict__ wh,
                 float* __restrict__ out) {
  __shared__ unsigned char lds[131072];

  // bijective XCD swizzle (512 blocks % 8 == 0): each XCD gets 64 contiguous
  const int orig = blockIdx.x;
  const int wg = (orig & 7) * 64 + (orig >> 3);
  const int mt = wg >> 4;          // 0..31
  const int nt = wg & 15;          // 0..15 fastest -> neighbors share A panel
  const int blockM = mt * BM;
  const int blockN = nt * BN;

  const int tid = threadIdx.x;
  const int lane = tid & 63;
  const int wave = tid >> 6;       // 0..7
  const int wm = wave >> 2;        // 0..1  (M half of tile)
  const int wn = wave & 3;         // 0..3  (N quarter of tile)

  // ---- staging addresses: one half-tile = 256 rows x 32 f16 = 1024 chunks,
  //      512 threads x 2 issues; LDS dest linear in slot (lane-contiguous).
  const _Float16* aSrc[2];
  const _Float16* bSrc[2];
  unsigned ldsOff[2];
#pragma unroll
  for (int q = 0; q < 2; ++q) {
    int slot = q * 512 + tid;           // 0..1023
    int r = slot >> 2;                  // region row 0..255
    int c = slot & 3;                   // stored chunk
    int cd = c ^ ((r >> 1) & 3);        // data chunk (swizzle on the gather)
    aSrc[q] = xh + (size_t)(blockM + r) * IN_F + cd * 8;
    bSrc[q] = wh + (size_t)(blockN + r) * IN_F + cd * 8;
    ldsOff[q] = (unsigned)slot * 16;
  }

  // ---- fragment LDS offsets within a region (iter-invariant).
  // mh=1 is +64 rows = +4096 bytes; swizzle term invariant under +64.
  const int kg = lane >> 4;
  unsigned offA[4], offB[4];
#pragma unroll
  for (int t = 0; t < 4; ++t) {
    int ar = wm * 128 + t * 16 + (lane & 15);
    offA[t] = (unsigned)(ar * 64 + ((kg ^ ((ar >> 1) & 3)) * 16));
    int br = wn * 64 + t * 16 + (lane & 15);
    offB[t] = (unsigned)(br * 64 + ((kg ^ ((br >> 1) & 3)) * 16));
  }

  f32x4 acc[8][4];
#pragma unroll
  for (int i = 0; i < 8; ++i)
#pragma unroll
    for (int j = 0; j < 4; ++j) acc[i][j] = (f32x4){0.f, 0.f, 0.f, 0.f};

#define STG(SRC, LDSBASE, KOFS)                                      \
  {                                                                  \
    async16(SRC[0] + (KOFS), lds + (LDSBASE) + ldsOff[0]);           \
    async16(SRC[1] + (KOFS), lds + (LDSBASE) + ldsOff[1]);           \
  }

  // ---- prologue: tile0 fully + tile1 {B_k0, A_k0, B_k1}; keep 6 in flight.
  STG(aSrc, 0, 0);                 // A_k0(0)
  STG(bSrc, 16384, 0);             // B_k0(0)
  STG(aSrc, 32768, 32);            // A_k1(0)
  STG(bSrc, 49152, 32);            // B_k1(0)
  STG(bSrc, 65536 + 16384, 64);    // B_k0(1)
  STG(aSrc, 65536 + 0, 64);        // A_k0(1)
  STG(bSrc, 65536 + 49152, 96);    // B_k1(1)
  asm volatile("s_waitcnt vmcnt(6)" ::: "memory");  // tile0 resident
  __builtin_amdgcn_s_barrier();

#pragma unroll 2
  for (int t = 0; t < NT; ++t) {
    const unsigned base = (unsigned)(t & 1) << 16;
    const unsigned baseN = base ^ 65536u;
    const int kof1 = (t + 1) * BK;
    const int kof2 = (t + 2) * BK;
    const bool ok1 = (t + 1) < NT;
    const bool ok2 = (t + 2) < NT;

    if (t >= NT - 2) {  // epilogue tiles: drain (tail stages were skipped)
      asm volatile("s_waitcnt vmcnt(0)" ::: "memory");
      __builtin_amdgcn_s_barrier();
    }

    f16x8 aF[4], bF[4];

    // ---------------- P1: (mh=0, k0) ----------------
#pragma unroll
    for (int i = 0; i < 4; ++i)
      aF[i] = *(const f16x8*)(lds + base + offA[i]);
#pragma unroll
    for (int j = 0; j < 4; ++j)
      bF[j] = *(const f16x8*)(lds + base + 16384 + offB[j]);
    if (ok1) STG(aSrc, baseN + 32768, kof1 + 32);   // A_k1(t+1)
    __builtin_amdgcn_s_barrier();
    asm volatile("s_waitcnt lgkmcnt(0)" ::: "memory");
    __builtin_amdgcn_sched_barrier(0);
    __builtin_amdgcn_s_setprio(1);
#pragma unroll
    for (int i = 0; i < 4; ++i)
#pragma unroll
      for (int j = 0; j < 4; ++j)
        acc[i][j] = __builtin_amdgcn_mfma_f32_16x16x32_f16(aF[i], bF[j], acc[i][j], 0, 0, 0);
    __builtin_amdgcn_s_setprio(0);
    __builtin_amdgcn_s_barrier();

    // ---------------- P2: (mh=1, k0)  [bF reused] ----------------
#pragma unroll
    for (int i = 0; i < 4; ++i)
      aF[i] = *(const f16x8*)(lds + base + 4096 + offA[i]);
    if (ok2) STG(bSrc, base + 16384, kof2);         // B_k0(t+2) (region free after P1)
    __builtin_amdgcn_s_barrier();
    asm volatile("s_waitcnt lgkmcnt(0)" ::: "memory");
    __builtin_amdgcn_sched_barrier(0);
    __builtin_amdgcn_s_setprio(1);
#pragma unroll
    for (int i = 0; i < 4; ++i)
#pragma unroll
      for (int j = 0; j < 4; ++j)
        acc[4 + i][j] = __builtin_amdgcn_mfma_f32_16x16x32_f16(aF[i], bF[j], acc[4 + i][j], 0, 0, 0);
    __builtin_amdgcn_s_setprio(0);
    __builtin_amdgcn_s_barrier();

    // ---------------- P3: (mh=0, k1) ----------------
#pragma unroll
    for (int i = 0; i < 4; ++i)
      aF[i] = *(const f16x8*)(lds + base + 32768 + offA[i]);
#pragma unroll
    for (int j = 0; j < 4; ++j)
      bF[j] = *(const f16x8*)(lds + base + 49152 + offB[j]);
    if (ok2) STG(aSrc, base + 0, kof2);             // A_k0(t+2) (free after P2)
    __builtin_amdgcn_s_barrier();
    asm volatile("s_waitcnt lgkmcnt(0)" ::: "memory");
    __builtin_amdgcn_sched_barrier(0);
    __builtin_amdgcn_s_setprio(1);
#pragma unroll
    for (int i = 0; i < 4; ++i)
#pragma unroll
      for (int j = 0; j < 4; ++j)
        acc[i][j] = __builtin_amdgcn_mfma_f32_16x16x32_f16(aF[i], bF[j], acc[i][j], 0, 0, 0);
    __builtin_amdgcn_s_setprio(0);
    __builtin_amdgcn_s_barrier();

    // ---------------- P4: (mh=1, k1)  [bF reused] ----------------
#pragma unroll
    for (int i = 0; i < 4; ++i)
      aF[i] = *(const f16x8*)(lds + base + 32768 + 4096 + offA[i]);
    if (ok2) STG(bSrc, base + 49152, kof2 + 32);    // B_k1(t+2) (free after P3)
    // once-per-K-tile counted wait: leaves the 3 newest half-tiles (6 loads)
    // in flight; in-order completion guarantees all of tile t+1 resident.
    asm volatile("s_waitcnt vmcnt(6)" ::: "memory");
    __builtin_amdgcn_s_barrier();
    asm volatile("s_waitcnt lgkmcnt(0)" ::: "memory");
    __builtin_amdgcn_sched_barrier(0);
    __builtin_amdgcn_s_setprio(1);
#pragma unroll
    for (int i = 0; i < 4; ++i)
#pragma unroll
      for (int j = 0; j < 4; ++j)
        acc[4 + i][j] = __builtin_amdgcn_mfma_f32_16x16x32_f16(aF[i], bF[j], acc[4 + i][j], 0, 0, 0);
    __builtin_amdgcn_s_setprio(0);
    __builtin_amdgcn_s_barrier();
  }
#undef STG

  // C/D layout col=lane&15, row=(lane>>4)*4+reg  [measured m89/m91]
  const int col0 = blockN + wn * 64 + (lane & 15);
  const int row0 = blockM + wm * 128 + (lane >> 4) * 4;
#pragma unroll
  for (int i = 0; i < 8; ++i)
#pragma unroll
    for (int j = 0; j < 4; ++j) {
      float* op = out + (size_t)(row0 + i * 16) * OUT_F + col0 + j * 16;
#pragma unroll
      for (int rr = 0; rr < 4; ++rr) op[(size_t)rr * OUT_F] = acc[i][j][rr];
    }
}

// ================================================================ FALLBACK
// fp32 VALU GEMM out = x @ W^T (64x64 tile), then out += (x V s) U^T.
__global__ __launch_bounds__(256)
void fb_gemm(const float* __restrict__ x, const float* __restrict__ W,
             float* __restrict__ out) {
  __shared__ float xs[64][17];
  __shared__ float wsm[64][17];
  const int mt = blockIdx.x >> 6;
  const int ntile = blockIdx.x & 63;
  const int bM = mt * 64, bN = ntile * 64;
  const int t = threadIdx.x;
  const int lr = t >> 2, lc = (t & 3) * 4;
  const int tm = t >> 4, tn = t & 15;

  float acc[4][4];
#pragma unroll
  for (int i = 0; i < 4; ++i)
#pragma unroll
    for (int j = 0; j < 4; ++j) acc[i][j] = 0.f;

  for (int kk = 0; kk < IN_F; kk += 16) {
    float4 xa = *(const float4*)(x + (size_t)(bM + lr) * IN_F + kk + lc);
    float4 wa = *(const float4*)(W + (size_t)(bN + lr) * IN_F + kk + lc);
    xs[lr][lc + 0] = xa.x; xs[lr][lc + 1] = xa.y;
    xs[lr][lc + 2] = xa.z; xs[lr][lc + 3] = xa.w;
    wsm[lr][lc + 0] = wa.x; wsm[lr][lc + 1] = wa.y;
    wsm[lr][lc + 2] = wa.z; wsm[lr][lc + 3] = wa.w;
    __syncthreads();
#pragma unroll
    for (int k = 0; k < 16; ++k) {
      float a[4], b[4];
#pragma unroll
      for (int i = 0; i < 4; ++i) a[i] = xs[tm * 4 + i][k];
#pragma unroll
      for (int j = 0; j < 4; ++j) b[j] = wsm[tn * 4 + j][k];
#pragma unroll
      for (int i = 0; i < 4; ++i)
#pragma unroll
        for (int j = 0; j < 4; ++j) acc[i][j] += a[i] * b[j];
    }
    __syncthreads();
  }
#pragma unroll
  for (int i = 0; i < 4; ++i)
#pragma unroll
    for (int j = 0; j < 4; ++j)
      out[(size_t)(bM + tm * 4 + i) * OUT_F + bN + tn * 4 + j] = acc[i][j];
}

__global__ void fb_xv(const float* __restrict__ x, const float* __restrict__ V,
                      const float* __restrict__ S, float* __restrict__ xv) {
  int m = blockIdx.x * 4 + (threadIdx.x >> 6);
  int lane = threadIdx.x & 63;
  float a[RANK];
#pragma unroll
  for (int r = 0; r < RANK; ++r) a[r] = 0.f;
  for (int k = lane; k < IN_F; k += 64) {
    float xe = x[(size_t)m * IN_F + k];
    const float4* vp = (const float4*)(V + (size_t)k * RANK);
#pragma unroll
    for (int q = 0; q < 4; ++q) {
      float4 vv = vp[q];
      a[q * 4 + 0] += xe * vv.x; a[q * 4 + 1] += xe * vv.y;
      a[q * 4 + 2] += xe * vv.z; a[q * 4 + 3] += xe * vv.w;
    }
  }
#pragma unroll
  for (int r = 0; r < RANK; ++r)
    for (int off = 32; off; off >>= 1) a[r] += __shfl_down(a[r], off);
  if (lane == 0) {
#pragma unroll
    for (int r = 0; r < RANK; ++r) xv[(size_t)m * RANK + r] = a[r] * S[r];
  }
}

__global__ void fb_add(const float* __restrict__ xv, const float* __restrict__ U,
                       float* __restrict__ out) {
  size_t t = (size_t)blockIdx.x * 256 + threadIdx.x;
  int m = (int)(t >> 12), o = (int)(t & 4095);
  const float* xr = xv + (size_t)m * RANK;
  const float* ur = U + (size_t)o * RANK;
  float d = 0.f;
#pragma unroll
  for (int r = 0; r < RANK; ++r) d += xr[r] * ur[r];
  out[t] += d;
}

// ---------------------------------------------------------------- launch
extern "C" void kernel_launch(void* const* d_in, const int* in_sizes, int n_in,
                              void* d_out, int out_size, void* d_ws, size_t ws_size,
                              hipStream_t stream) {
  const float* x = (const float*)d_in[0];
  const float* W = (const float*)d_in[1];
  const float* U = (const float*)d_in[2];
  const float* s = (const float*)d_in[3];
  const float* V = (const float*)d_in[4];
  float* out = (float*)d_out;

  // workspace: xh (8192*4096 f16) + wh (4096*4096 f16) = 100 MiB
  const size_t need = ((size_t)M_ROWS * IN_F + (size_t)OUT_F * IN_F) * 2;
  if (ws_size >= need) {
    _Float16* xh = (_Float16*)d_ws;
    _Float16* wh = xh + (size_t)M_ROWS * IN_F;
    // fused prep: x->f16 (blocks <4096, grid-stride) || W+UsV^T->f16 (2048 blocks)
    prep_kernel<<<SPLIT_BLOCKS + ((IN_F / 4) * (OUT_F / 8)) / 256, 256, 0, stream>>>(
        x, xh, W, U, s, V, wh);
    gemm_kernel<<<(M_ROWS / BM) * (OUT_F / BN), 512, 0, stream>>>(xh, wh, out);
  } else {
    float* xv = (float*)d_ws;  // 8192*16 f32 = 512 KiB
    fb_gemm<<<(M_ROWS / 64) * (OUT_F / 64), 256, 0, stream>>>(x, W, out);
    fb_xv<<<M_ROWS / 4, 256, 0, stream>>>(x, V, s, xv);
    fb_add<<<(size_t)M_ROWS * OUT_F / 256, 256, 0, stream>>>(xv, U, out);
  }
}